// Round 2
// baseline (251.959 us; speedup 1.0000x reference)
//
#include <hip/hip_runtime.h>

#define SEG 24
#define DD  32
#define HEPS 1e-7f
#define N_ITERS 10

typedef _Float16 half2_t __attribute__((ext_vector_type(2)));

__device__ __forceinline__ float frcp(float x) { return __builtin_amdgcn_rcpf(x); }

// coef = arccosh(alpha)/sqrt(alpha^2-1), caller guarantees alpha >= 1+1e-7
__device__ __forceinline__ float acosh_coef(float alpha) {
    float am = fmaf(alpha, alpha, -1.0f);
    float s  = sqrtf(am);
    return __logf(alpha + s) * frcp(s);
}

__global__ __launch_bounds__(256, 1)
void slmw_kernel(const float* __restrict__ x0, const float* __restrict__ x1,
                 const float* __restrict__ x2, const float* __restrict__ x3,
                 const float* __restrict__ W0, const float* __restrict__ b0,
                 const float* __restrict__ W1, const float* __restrict__ b1,
                 const float* __restrict__ W2, const float* __restrict__ b2,
                 const float* __restrict__ W3, const float* __restrict__ b3,
                 const float* __restrict__ es, const float* __restrict__ lw,
                 float* __restrict__ out, int n_items)
{
    const int item = blockIdx.x * blockDim.x + threadIdx.x;
    if (item >= n_items) return;

    const float ts = tanhf(es[0]);

    float l0 = lw[0], l1 = lw[1], l2 = lw[2], l3 = lw[3];
    float mx = fmaxf(fmaxf(l0, l1), fmaxf(l2, l3));
    float e0 = __expf(l0 - mx), e1 = __expf(l1 - mx),
          e2 = __expf(l2 - mx), e3 = __expf(l3 - mx);
    float inv = frcp(e0 + e1 + e2 + e3);
    float w4[4] = { e0 * inv, e1 * inv, e2 * inv, e3 * inv };

    const float* xs[4] = { x0, x1, x2, x3 };
    const float* Ws[4] = { W0, W1, W2, W3 };
    const float* bs[4] = { b0, b1, b2, b3 };

    const size_t base = (size_t)item * SEG;
    const size_t osz  = (size_t)n_items * DD;

    half2_t h2[4][DD / 2];          // fusion copy of h, packed f16 (64 VGPRs)

    // ---- encode + to_hyperbolic, one-stream-ahead input prefetch ----
    float4 buf[2][SEG / 4];
    {
        const float4* sp = reinterpret_cast<const float4*>(xs[0] + base);
        #pragma unroll
        for (int j = 0; j < SEG / 4; ++j) buf[0][j] = sp[j];
    }

    #pragma unroll
    for (int s = 0; s < 4; ++s) {
        if (s < 3) {
            const float4* sp = reinterpret_cast<const float4*>(xs[s + 1] + base);
            #pragma unroll
            for (int j = 0; j < SEG / 4; ++j) buf[(s + 1) & 1][j] = sp[j];
        }
        float seg[SEG];
        #pragma unroll
        for (int j = 0; j < SEG / 4; ++j) {
            float4 v = buf[s & 1][j];
            seg[4*j+0] = v.x; seg[4*j+1] = v.y; seg[4*j+2] = v.z; seg[4*j+3] = v.w;
        }

        float u[DD];
        #pragma unroll
        for (int d = 0; d < DD; ++d) {
            float z = bs[s][d];                            // wave-uniform s_load
            #pragma unroll
            for (int k = 0; k < SEG; ++k)
                z = fmaf(seg[k], Ws[s][d * SEG + k], z);
            u[d] = z * ts;
        }

        // safe_expmap0: sq_L = sum(u^2) - 2*u0^2, 4-way partials
        float q[4] = {0.f, 0.f, 0.f, 0.f};
        #pragma unroll
        for (int d = 0; d < DD; ++d) q[d & 3] = fmaf(u[d], u[d], q[d & 3]);
        float sq = (q[0] + q[1]) + (q[2] + q[3]) - 2.0f * u[0] * u[0];
        sq = fmaxf(sq, 1e-12f);
        float nrm = sqrtf(sq);
        float ep = __expf(nrm), em = frcp(ep);
        float sh = 0.5f * (ep - em);
        float sc = sh * frcp(fmaxf(nrm, HEPS));

        float y[DD];
        float r[4] = {0.f, 0.f, 0.f, 0.f};
        #pragma unroll
        for (int d = 1; d < DD; ++d) {
            float yv = sc * u[d];
            y[d] = yv;
            r[d & 3] = fmaf(yv, yv, r[d & 3]);
        }
        y[0] = sqrtf(1.0f + (r[0] + r[1]) + (r[2] + r[3]));   // projx time comp

        float* op = out + (size_t)s * osz + (size_t)item * DD;
        #pragma unroll
        for (int j = 0; j < DD / 4; ++j) {
            float4 v = { y[4*j+0], y[4*j+1], y[4*j+2], y[4*j+3] };
            reinterpret_cast<float4*>(op)[j] = v;
        }
        #pragma unroll
        for (int p = 0; p < DD / 2; ++p)
            h2[s][p] = (half2_t){ (_Float16)y[2*p], (_Float16)y[2*p+1] };
    }

    // ---- fusion init: t0 = sum_s w_s * logmap0(h_s); mean = projx(expmap0(t0)) ----
    float mean[DD];
    {
        float t0[DD];
        #pragma unroll
        for (int d = 0; d < DD; ++d) t0[d] = 0.0f;
        #pragma unroll
        for (int s = 0; s < 4; ++s) {
            float y0    = (float)h2[s][0][0];
            float alpha = fmaxf(y0, 1.0f + HEPS);
            float c     = w4[s] * acosh_coef(alpha);
            t0[0] = fmaf(c, y0 - alpha, t0[0]);
            #pragma unroll
            for (int d = 1; d < DD; ++d)
                t0[d] = fmaf(c, (float)h2[s][d >> 1][d & 1], t0[d]);
        }
        float q[4] = {0.f, 0.f, 0.f, 0.f};
        #pragma unroll
        for (int d = 0; d < DD; ++d) q[d & 3] = fmaf(t0[d], t0[d], q[d & 3]);
        float sq = (q[0] + q[1]) + (q[2] + q[3]) - 2.0f * t0[0] * t0[0];
        sq = fmaxf(sq, 1e-12f);
        float nrm = sqrtf(sq);
        float ep = __expf(nrm), em = frcp(ep);
        float sh = 0.5f * (ep - em);
        float sc = sh * frcp(fmaxf(nrm, HEPS));
        float r[4] = {0.f, 0.f, 0.f, 0.f};
        #pragma unroll
        for (int d = 1; d < DD; ++d) {
            float yv = sc * t0[d];
            mean[d] = yv;
            r[d & 3] = fmaf(yv, yv, r[d & 3]);
        }
        mean[0] = sqrtf(1.0f + (r[0] + r[1]) + (r[2] + r[3]));
    }

    // ---- Frechet refinement (global early-exit dropped: sub-tolerance drift) ----
    for (int it = 0; it < N_ITERS; ++it) {
        float wv[DD];
        #pragma unroll
        for (int d = 0; d < DD; ++d) wv[d] = 0.0f;

        #pragma unroll
        for (int s = 0; s < 4; ++s) {
            // alpha = -<m,h>_L = 2*(m0*h0) - sum_all(m_d*h_d)
            float q[4] = {0.f, 0.f, 0.f, 0.f};
            #pragma unroll
            for (int d = 0; d < DD; ++d)
                q[d & 3] = fmaf((float)h2[s][d >> 1][d & 1], mean[d], q[d & 3]);
            float E = (q[0] + q[1]) + (q[2] + q[3]);
            float T = mean[0] * (float)h2[s][0][0];
            float alpha = fmaxf(2.0f * T - E, 1.0f + HEPS);
            float c = w4[s] * acosh_coef(alpha);
            #pragma unroll
            for (int d = 0; d < DD; ++d) {
                float t = fmaf(-alpha, mean[d], (float)h2[s][d >> 1][d & 1]);
                wv[d] = fmaf(c, t, wv[d]);
            }
        }

        // u = 0.5*wv ; mean = projx(cosh(n)*mean + sinh(n)*u/max(n,eps))
        float q[4] = {0.f, 0.f, 0.f, 0.f};
        #pragma unroll
        for (int d = 0; d < DD; ++d) q[d & 3] = fmaf(wv[d], wv[d], q[d & 3]);
        float sq = (q[0] + q[1]) + (q[2] + q[3]) - 2.0f * wv[0] * wv[0];
        sq = fmaxf(0.25f * sq, 1e-12f);
        float nrm = sqrtf(sq);
        float ep = __expf(nrm), em = frcp(ep);
        float ch = 0.5f * (ep + em);
        float sh = 0.5f * (ep - em);
        float sc = 0.5f * sh * frcp(fmaxf(nrm, HEPS));
        float r[4] = {0.f, 0.f, 0.f, 0.f};
        #pragma unroll
        for (int d = 1; d < DD; ++d) {
            float yv = fmaf(ch, mean[d], sc * wv[d]);
            mean[d] = yv;
            r[d & 3] = fmaf(yv, yv, r[d & 3]);
        }
        mean[0] = sqrtf(1.0f + (r[0] + r[1]) + (r[2] + r[3]));
    }

    float* op = out + (size_t)4 * osz + (size_t)item * DD;
    #pragma unroll
    for (int j = 0; j < DD / 4; ++j) {
        float4 v = { mean[4*j+0], mean[4*j+1], mean[4*j+2], mean[4*j+3] };
        reinterpret_cast<float4*>(op)[j] = v;
    }
}

extern "C" void kernel_launch(void* const* d_in, const int* in_sizes, int n_in,
                              void* d_out, int out_size, void* d_ws, size_t ws_size,
                              hipStream_t stream)
{
    const float* x0 = (const float*)d_in[0];
    const float* x1 = (const float*)d_in[1];
    const float* x2 = (const float*)d_in[2];
    const float* x3 = (const float*)d_in[3];
    const float* W0 = (const float*)d_in[4];
    const float* b0 = (const float*)d_in[5];
    const float* W1 = (const float*)d_in[6];
    const float* b1 = (const float*)d_in[7];
    const float* W2 = (const float*)d_in[8];
    const float* b2 = (const float*)d_in[9];
    const float* W3 = (const float*)d_in[10];
    const float* b3 = (const float*)d_in[11];
    const float* es = (const float*)d_in[12];
    const float* lw = (const float*)d_in[13];

    const int n_items = in_sizes[0] / SEG;
    const int block = 256;
    const int grid  = (n_items + block - 1) / block;

    slmw_kernel<<<grid, block, 0, stream>>>(x0, x1, x2, x3,
                                            W0, b0, W1, b1, W2, b2, W3, b3,
                                            es, lw, (float*)d_out, n_items);
}